// Round 2
// baseline (793.556 us; speedup 1.0000x reference)
//
#include <hip/hip_runtime.h>
#include <hip/hip_bf16.h>

// ---------------------------------------------------------------------------
// MultiHeadAttention: B=4, L=2048, D_MODEL=1024, H=16, Dh=64, causal + key mask
// y = softmax((XWq^T)(XWk^T)^T / sqrt(64) + mask) (XWv^T) Wo^T
// Device dtype of float tensors is detected at runtime (bf16 vs f32) — the
// harness docs say dtypes follow the reference (f32), but this harness family
// often bf16-ifies; round-1 NaN is consistent with f32-read-as-bf16. A tiny
// detector kernel samples `query` and all kernels branch uniformly on the flag.
// ---------------------------------------------------------------------------

#define SEQ   2048
#define DM    1024
#define NH    16
#define BATCH 4

typedef __attribute__((ext_vector_type(8))) short bf16x8;   // 8 bf16 (4 VGPRs)
typedef __attribute__((ext_vector_type(4))) float f32x4;    // MFMA C/D

#define MFMA16(a, b, c) __builtin_amdgcn_mfma_f32_16x16x32_bf16((a), (b), (c), 0, 0, 0)

// f32 -> bf16 bits, round-to-nearest-even
__device__ inline short f2bf(float f) {
    unsigned u = __float_as_uint(f);
    unsigned r = (u + 0x7fffu + ((u >> 16) & 1u)) >> 16;
    return (short)r;
}

// async global->LDS, 16B per lane. LDS dest must be linear: base + lane*16.
__device__ inline void gload_lds16(const short* g, short* l) {
    __builtin_amdgcn_global_load_lds(
        (const __attribute__((address_space(1))) unsigned int*)g,
        (__attribute__((address_space(3))) unsigned int*)l,
        16, 0, 0);
}

// ---------------------------------------------------------------------------
// dtype detector: even-indexed shorts of a bf16 tensor are bf16 values with
// exponent in ~[100,140]; of an f32 tensor they are low mantissa halves with
// uniform exponent bits (~16% in range). Majority vote over 4096 samples.
// flag = 1 -> f32, 0 -> bf16.
// ---------------------------------------------------------------------------
__global__ void detect_dtype(const unsigned short* __restrict__ q, int* __restrict__ flag) {
    __shared__ int tot;
    const int t = threadIdx.x;
    if (t == 0) tot = 0;
    __syncthreads();
    int cnt = 0;
    for (int i = t; i < 4096; i += 256) {
        const unsigned short s = q[2 * i];
        const int e = (s >> 7) & 0xff;
        cnt += (e >= 100 && e <= 140) ? 1 : 0;
    }
    atomicAdd(&tot, cnt);
    __syncthreads();
    if (t == 0) *flag = (tot < 2048) ? 1 : 0;
}

// ---------------------------------------------------------------------------
// GEMM:  Y[M][N] = X[M][K] @ W[N][K]^T  (f32 accumulate)
// 128x128 tile / block, 4 waves in 2x2 of 64x64, BK=32.
// Per-operand dtype: bf16 path stages via global_load_lds (16B); f32 path
// reg-stages float4 pairs, converts, ds_write_b128.
// ---------------------------------------------------------------------------
__global__ __launch_bounds__(256)
void gemm_dual(const void* __restrict__ Xv, const void* __restrict__ Wv,
               void* __restrict__ Yv, const int* __restrict__ flag,
               int aDyn, int bDyn, int yDyn, int M, int N, int K) {
    __shared__ short lds_a[128 * 32];
    __shared__ short lds_b[128 * 32];

    const int isf = *flag;
    const bool fA = aDyn && isf, fB = bDyn && isf, fY = yDyn && isf;

    const short* Xh = (const short*)Xv;
    const float* Xf = (const float*)Xv;
    const short* Wh = (const short*)Wv;
    const float* Wf = (const float*)Wv;
    short*       Yh = (short*)Yv;
    float*       Yf = (float*)Yv;

    const int t    = threadIdx.x;
    const int lane = t & 63;
    const int l16  = lane & 15;
    const int lhi  = lane >> 4;
    const int w    = t >> 6;
    const int wr   = (w >> 1) * 64;
    const int wc   = (w & 1) * 64;
    const int bm   = blockIdx.x * 128;
    const int bn   = blockIdx.y * 128;

    f32x4 acc[4][4] = {};

    // staging: 512 chunks of 8 elems; chunk c -> row c>>2, k-off (c&3)*8
    const int c0 = t, c1 = t + 256;
    const int ra0 = c0 >> 2, ka0 = (c0 & 3) * 8;
    const int ra1 = c1 >> 2, ka1 = (c1 & 3) * 8;

    for (int kt = 0; kt < K; kt += 32) {
        __syncthreads();
        if (fA) {
            const float* s0 = Xf + (size_t)(bm + ra0) * K + kt + ka0;
            const float* s1 = Xf + (size_t)(bm + ra1) * K + kt + ka1;
            f32x4 lo0 = *(const f32x4*)s0, hi0 = *(const f32x4*)(s0 + 4);
            f32x4 lo1 = *(const f32x4*)s1, hi1 = *(const f32x4*)(s1 + 4);
            bf16x8 r0, r1;
#pragma unroll
            for (int j = 0; j < 4; ++j) {
                r0[j] = f2bf(lo0[j]); r0[j + 4] = f2bf(hi0[j]);
                r1[j] = f2bf(lo1[j]); r1[j + 4] = f2bf(hi1[j]);
            }
            *(bf16x8*)&lds_a[c0 * 8] = r0;
            *(bf16x8*)&lds_a[c1 * 8] = r1;
        } else {
            gload_lds16(Xh + (size_t)(bm + ra0) * K + kt + ka0, lds_a + c0 * 8);
            gload_lds16(Xh + (size_t)(bm + ra1) * K + kt + ka1, lds_a + c1 * 8);
        }
        if (fB) {
            const float* s0 = Wf + (size_t)(bn + ra0) * K + kt + ka0;
            const float* s1 = Wf + (size_t)(bn + ra1) * K + kt + ka1;
            f32x4 lo0 = *(const f32x4*)s0, hi0 = *(const f32x4*)(s0 + 4);
            f32x4 lo1 = *(const f32x4*)s1, hi1 = *(const f32x4*)(s1 + 4);
            bf16x8 r0, r1;
#pragma unroll
            for (int j = 0; j < 4; ++j) {
                r0[j] = f2bf(lo0[j]); r0[j + 4] = f2bf(hi0[j]);
                r1[j] = f2bf(lo1[j]); r1[j + 4] = f2bf(hi1[j]);
            }
            *(bf16x8*)&lds_b[c0 * 8] = r0;
            *(bf16x8*)&lds_b[c1 * 8] = r1;
        } else {
            gload_lds16(Wh + (size_t)(bn + ra0) * K + kt + ka0, lds_b + c0 * 8);
            gload_lds16(Wh + (size_t)(bn + ra1) * K + kt + ka1, lds_b + c1 * 8);
        }
        __syncthreads();  // drains vmcnt + lgkmcnt before s_barrier

        bf16x8 af[4], bfr[4];
#pragma unroll
        for (int mi = 0; mi < 4; ++mi)
            af[mi] = *(const bf16x8*)&lds_a[(wr + mi * 16 + l16) * 32 + lhi * 8];
#pragma unroll
        for (int ni = 0; ni < 4; ++ni)
            bfr[ni] = *(const bf16x8*)&lds_b[(wc + ni * 16 + l16) * 32 + lhi * 8];
#pragma unroll
        for (int mi = 0; mi < 4; ++mi)
#pragma unroll
            for (int ni = 0; ni < 4; ++ni)
                acc[mi][ni] = MFMA16(af[mi], bfr[ni], acc[mi][ni]);
    }

    // epilogue: C/D layout col = lane&15, row = (lane>>4)*4 + reg
#pragma unroll
    for (int mi = 0; mi < 4; ++mi) {
#pragma unroll
        for (int ni = 0; ni < 4; ++ni) {
            const int row0 = bm + wr + mi * 16 + lhi * 4;
            const int col  = bn + wc + ni * 16 + l16;
#pragma unroll
            for (int r = 0; r < 4; ++r) {
                if (fY) Yf[(size_t)(row0 + r) * N + col] = acc[mi][ni][r];
                else    Yh[(size_t)(row0 + r) * N + col] = f2bf(acc[mi][ni][r]);
            }
        }
    }
}

// ---------------------------------------------------------------------------
// Flash attention (causal + key-valid mask), one block per (b, h, 64-row qtile)
// 4 waves, each owns 16 q-rows. KV tiles of 32. Online softmax in f32.
// Inputs are always my own bf16 ws buffers.
// ---------------------------------------------------------------------------
__global__ __launch_bounds__(256)
void attn_fwd(const short* __restrict__ Q, const short* __restrict__ K,
              const short* __restrict__ V, const int* __restrict__ amask,
              short* __restrict__ ctx) {
    __shared__ short k_lds[32 * 64];    // K tile  [k][d]
    __shared__ short vt_lds[64 * 32];   // V tile transposed [d][k]
    __shared__ short p_lds[4][16 * 32]; // per-wave P buffer

    const int t    = threadIdx.x;
    const int lane = t & 63;
    const int l16  = lane & 15;
    const int lhi  = lane >> 4;
    const int w    = t >> 6;
    const int qt   = blockIdx.x;
    const int bh   = blockIdx.y;
    const int b    = bh >> 4;
    const int h    = bh & 15;

    const short* Qh = Q + (size_t)b * SEQ * DM + h * 64;
    const short* Kh = K + (size_t)b * SEQ * DM + h * 64;
    const short* Vh = V + (size_t)b * SEQ * DM + h * 64;
    const int*   mb = amask + b * SEQ;

    const int q0 = qt * 64 + w * 16;  // this wave's first q row

    bf16x8 qf[2];
#pragma unroll
    for (int df = 0; df < 2; ++df)
        qf[df] = *(const bf16x8*)&Qh[(q0 + l16) * DM + df * 32 + lhi * 8];

    float m_r[4], l_r[4];
    f32x4 o[4] = {};
#pragma unroll
    for (int r = 0; r < 4; ++r) { m_r[r] = -1e30f; l_r[r] = 0.f; }

    const int vrow = t >> 3, vch = t & 7;  // staging coords (32 rows x 8 chunks)
    const int nkt  = qt * 2 + 2;           // causal: tiles covering k <= q0+63

    for (int kt = 0; kt < nkt; ++kt) {
        __syncthreads();
        gload_lds16(Kh + (kt * 32 + vrow) * DM + vch * 8, k_lds + t * 8);
        bf16x8 vv = *(const bf16x8*)&Vh[(kt * 32 + vrow) * DM + vch * 8];
#pragma unroll
        for (int j = 0; j < 8; ++j)
            vt_lds[(vch * 8 + j) * 32 + vrow] = ((const short*)&vv)[j];
        __syncthreads();

        // S = Q K^T
        f32x4 s[2] = {};
#pragma unroll
        for (int nf = 0; nf < 2; ++nf)
#pragma unroll
            for (int df = 0; df < 2; ++df) {
                bf16x8 kf = *(const bf16x8*)&k_lds[(nf * 16 + l16) * 64 + df * 32 + lhi * 8];
                s[nf] = MFMA16(qf[df], kf, s[nf]);
            }

        float p[2][4], tile_max[4];
#pragma unroll
        for (int r = 0; r < 4; ++r) tile_max[r] = -1e30f;
#pragma unroll
        for (int nf = 0; nf < 2; ++nf) {
            const int   kc     = kt * 32 + nf * 16 + l16;
            const float mvalid = (mb[kc] != 0) ? 0.f : -1e30f;
#pragma unroll
            for (int r = 0; r < 4; ++r) {
                const int qr = q0 + lhi * 4 + r;
                float sv = s[nf][r] * 0.125f + mvalid;
                if (kc > qr) sv = -1e30f;
                p[nf][r]    = sv;
                tile_max[r] = fmaxf(tile_max[r], sv);
            }
        }
#pragma unroll
        for (int r = 0; r < 4; ++r)
#pragma unroll
            for (int xm = 1; xm < 16; xm <<= 1)
                tile_max[r] = fmaxf(tile_max[r], __shfl_xor(tile_max[r], xm, 64));

        float alpha[4], rs[4];
#pragma unroll
        for (int r = 0; r < 4; ++r) {
            const float mnew = fmaxf(m_r[r], tile_max[r]);
            alpha[r] = __expf(m_r[r] - mnew);
            m_r[r]   = mnew;
            const float p0 = __expf(p[0][r] - mnew);
            const float p1 = __expf(p[1][r] - mnew);
            p[0][r] = p0; p[1][r] = p1;
            rs[r] = p0 + p1;
        }
#pragma unroll
        for (int r = 0; r < 4; ++r) {
#pragma unroll
            for (int xm = 1; xm < 16; xm <<= 1)
                rs[r] += __shfl_xor(rs[r], xm, 64);
            l_r[r] = alpha[r] * l_r[r] + rs[r];
        }
#pragma unroll
        for (int df = 0; df < 4; ++df)
#pragma unroll
            for (int r = 0; r < 4; ++r)
                o[df][r] *= alpha[r];

        // P (C-layout) -> LDS bf16 -> reload as MFMA A fragment
#pragma unroll
        for (int nf = 0; nf < 2; ++nf)
#pragma unroll
            for (int r = 0; r < 4; ++r)
                p_lds[w][(lhi * 4 + r) * 32 + nf * 16 + l16] = f2bf(p[nf][r]);
        asm volatile("s_waitcnt lgkmcnt(0)" ::: "memory");

        const bf16x8 pa = *(const bf16x8*)&p_lds[w][l16 * 32 + lhi * 8];
#pragma unroll
        for (int df = 0; df < 4; ++df) {
            bf16x8 vf = *(const bf16x8*)&vt_lds[(df * 16 + l16) * 32 + lhi * 8];
            o[df] = MFMA16(pa, vf, o[df]);
        }
    }

    // epilogue: O / l  -> ctx[b*SEQ + q][h*64 + d]  (always bf16)
#pragma unroll
    for (int r = 0; r < 4; ++r) {
        const float inv = 1.f / l_r[r];
        const int   qr  = q0 + lhi * 4 + r;
#pragma unroll
        for (int df = 0; df < 4; ++df)
            ctx[(size_t)(b * SEQ + qr) * DM + h * 64 + df * 16 + l16] =
                f2bf(o[df][r] * inv);
    }
}

// ---------------------------------------------------------------------------
extern "C" void kernel_launch(void* const* d_in, const int* in_sizes, int n_in,
                              void* d_out, int out_size, void* d_ws, size_t ws_size,
                              hipStream_t stream) {
    const void* query = d_in[0];
    const void* key   = d_in[1];
    const void* value = d_in[2];
    const int*  am    = (const int*)d_in[3];
    const void* Wq    = d_in[4];
    const void* Wk    = d_in[5];
    const void* Wv    = d_in[6];
    const void* Wo    = d_in[7];

    const size_t MTOK = (size_t)BATCH * SEQ;           // 8192 rows
    const size_t BUF  = MTOK * DM * sizeof(short);     // 16 MiB per buffer
    char* ws    = (char*)d_ws;
    int*  flag  = (int*)ws;                            // [0,4): dtype flag
    short* qp   = (short*)(ws + 1024 + 0 * BUF);
    short* kp   = (short*)(ws + 1024 + 1 * BUF);
    short* vp   = (short*)(ws + 1024 + 2 * BUF);
    short* ctx  = (short*)(ws + 1024 + 3 * BUF);

    detect_dtype<<<1, 256, 0, stream>>>((const unsigned short*)query, flag);

    const dim3 ggrid(MTOK / 128, DM / 128);  // (64, 8)
    gemm_dual<<<ggrid, 256, 0, stream>>>(query, Wq, qp, flag, 1, 1, 0, MTOK, DM, DM);
    gemm_dual<<<ggrid, 256, 0, stream>>>(key,   Wk, kp, flag, 1, 1, 0, MTOK, DM, DM);
    gemm_dual<<<ggrid, 256, 0, stream>>>(value, Wv, vp, flag, 1, 1, 0, MTOK, DM, DM);

    attn_fwd<<<dim3(SEQ / 64, BATCH * NH), 256, 0, stream>>>(qp, kp, vp, am, ctx);

    gemm_dual<<<ggrid, 256, 0, stream>>>(ctx, Wo, d_out, flag, 0, 1, 1, MTOK, DM, DM);
}

// Round 3
// 558.556 us; speedup vs baseline: 1.4207x; 1.4207x over previous
//
#include <hip/hip_runtime.h>
#include <hip/hip_bf16.h>

// ---------------------------------------------------------------------------
// MultiHeadAttention: B=4, L=2048, D_MODEL=1024, H=16, Dh=64, causal + key mask
// Round 3: swizzled LDS everywhere (pre-swizzled gload_lds sources), KVBLK=64,
// V^T produced by the V-projection GEMM epilogue, BK=64 GEMM, causal split,
// reversed q-tile dispatch. Dtype detector (bf16 vs f32) kept from round 2.
// ---------------------------------------------------------------------------

#define SEQ   2048
#define DM    1024
#define NH    16
#define BATCH 4

typedef __attribute__((ext_vector_type(8))) short bf16x8;   // 8 bf16 (4 VGPRs)
typedef __attribute__((ext_vector_type(4))) short short4v;  // 4 bf16 (8B store)
typedef __attribute__((ext_vector_type(4))) float f32x4;    // MFMA C/D

#define MFMA16(a, b, c) __builtin_amdgcn_mfma_f32_16x16x32_bf16((a), (b), (c), 0, 0, 0)

// f32 -> bf16 bits, round-to-nearest-even
__device__ inline short f2bf(float f) {
    unsigned u = __float_as_uint(f);
    unsigned r = (u + 0x7fffu + ((u >> 16) & 1u)) >> 16;
    return (short)r;
}

// async global->LDS, 16B per lane. LDS dest must be linear: base + lane*16.
__device__ inline void gload_lds16(const short* g, short* l) {
    __builtin_amdgcn_global_load_lds(
        (const __attribute__((address_space(1))) unsigned int*)g,
        (__attribute__((address_space(3))) unsigned int*)l,
        16, 0, 0);
}

// ---------------------------------------------------------------------------
// dtype detector: flag = 1 -> f32, 0 -> bf16. (proved itself in round 2)
// ---------------------------------------------------------------------------
__global__ void detect_dtype(const unsigned short* __restrict__ q, int* __restrict__ flag) {
    __shared__ int tot;
    const int t = threadIdx.x;
    if (t == 0) tot = 0;
    __syncthreads();
    int cnt = 0;
    for (int i = t; i < 4096; i += 256) {
        const unsigned short s = q[2 * i];
        const int e = (s >> 7) & 0xff;
        cnt += (e >= 100 && e <= 140) ? 1 : 0;
    }
    atomicAdd(&tot, cnt);
    __syncthreads();
    if (t == 0) *flag = (tot < 2048) ? 1 : 0;
}

// ---------------------------------------------------------------------------
// GEMM:  Y[M][N] = X[M][K] @ W[N][K]^T  (f32 accumulate), BK=64.
// LDS tiles [128][64] with XOR swizzle: LDS chunk q of row r holds logical
// 16B-chunk q^(r&7); reads XOR the chunk index -> conflict-free ds_read_b128.
// bf16 operands stage via global_load_lds (linear dest, pre-swizzled source);
// f32 operands reg-stage + convert + ds_write_b128 (same layout).
// yT: write Y transposed per (b,h) head-slice -> V^T for attention.
// ---------------------------------------------------------------------------
__global__ __launch_bounds__(256)
void gemm_dual(const void* __restrict__ Xv, const void* __restrict__ Wv,
               void* __restrict__ Yv, const int* __restrict__ flag,
               int aDyn, int bDyn, int yDyn, int yT, int N, int K) {
    __shared__ short lds_a[128 * 64];
    __shared__ short lds_b[128 * 64];

    const int isf = *flag;
    const bool fA = aDyn && isf, fB = bDyn && isf, fY = yDyn && isf;

    const short* Xh = (const short*)Xv;
    const float* Xf = (const float*)Xv;
    const short* Wh = (const short*)Wv;
    const float* Wf = (const float*)Wv;

    const int t    = threadIdx.x;
    const int lane = t & 63;
    const int l16  = lane & 15;
    const int lhi  = lane >> 4;
    const int w    = t >> 6;
    const int wr   = (w >> 1) * 64;
    const int wc   = (w & 1) * 64;
    const int bm   = blockIdx.x * 128;
    const int bn   = blockIdx.y * 128;

    f32x4 acc[4][4] = {};

    // staging chunks: 1024 per array (128 rows x 8), 4 per thread
    int rr[4], pp[4];
#pragma unroll
    for (int i = 0; i < 4; ++i) {
        const int c = t + i * 256;
        rr[i] = c >> 3;
        pp[i] = (c & 7) ^ (rr[i] & 7);
    }

    for (int kt = 0; kt < K; kt += 64) {
        __syncthreads();
        if (fA) {
#pragma unroll
            for (int i = 0; i < 4; ++i) {
                const float* s = Xf + (size_t)(bm + rr[i]) * K + kt + pp[i] * 8;
                f32x4 lo = *(const f32x4*)s, hi = *(const f32x4*)(s + 4);
                bf16x8 r;
#pragma unroll
                for (int j = 0; j < 4; ++j) { r[j] = f2bf(lo[j]); r[j + 4] = f2bf(hi[j]); }
                *(bf16x8*)&lds_a[(t + i * 256) * 8] = r;
            }
        } else {
#pragma unroll
            for (int i = 0; i < 4; ++i)
                gload_lds16(Xh + (size_t)(bm + rr[i]) * K + kt + pp[i] * 8,
                            lds_a + (t + i * 256) * 8);
        }
        if (fB) {
#pragma unroll
            for (int i = 0; i < 4; ++i) {
                const float* s = Wf + (size_t)(bn + rr[i]) * K + kt + pp[i] * 8;
                f32x4 lo = *(const f32x4*)s, hi = *(const f32x4*)(s + 4);
                bf16x8 r;
#pragma unroll
                for (int j = 0; j < 4; ++j) { r[j] = f2bf(lo[j]); r[j + 4] = f2bf(hi[j]); }
                *(bf16x8*)&lds_b[(t + i * 256) * 8] = r;
            }
        } else {
#pragma unroll
            for (int i = 0; i < 4; ++i)
                gload_lds16(Wh + (size_t)(bn + rr[i]) * K + kt + pp[i] * 8,
                            lds_b + (t + i * 256) * 8);
        }
        __syncthreads();  // drains vmcnt + lgkmcnt before s_barrier

#pragma unroll
        for (int kk = 0; kk < 2; ++kk) {
            bf16x8 af[4], bfr[4];
#pragma unroll
            for (int mi = 0; mi < 4; ++mi) {
                const int row = wr + mi * 16 + l16;
                af[mi] = *(const bf16x8*)&lds_a[row * 64 + ((kk * 4 + lhi) ^ (row & 7)) * 8];
            }
#pragma unroll
            for (int ni = 0; ni < 4; ++ni) {
                const int row = wc + ni * 16 + l16;
                bfr[ni] = *(const bf16x8*)&lds_b[row * 64 + ((kk * 4 + lhi) ^ (row & 7)) * 8];
            }
#pragma unroll
            for (int mi = 0; mi < 4; ++mi)
#pragma unroll
                for (int ni = 0; ni < 4; ++ni)
                    acc[mi][ni] = MFMA16(af[mi], bfr[ni], acc[mi][ni]);
        }
    }

    // epilogue: C/D layout col = lane&15, row = (lane>>4)*4 + reg
    if (yT) {
        // write Y^T per head-slice: YT[(b*DM + col)*SEQ + row%SEQ], packed 8B
        short* YT = (short*)Yv;
#pragma unroll
        for (int mi = 0; mi < 4; ++mi) {
#pragma unroll
            for (int ni = 0; ni < 4; ++ni) {
                const int row0 = bm + wr + mi * 16 + lhi * 4;
                const int col  = bn + wc + ni * 16 + l16;
                const int bi   = row0 >> 11;         // / SEQ
                const int rl0  = row0 & (SEQ - 1);
                short4v v;
#pragma unroll
                for (int r = 0; r < 4; ++r) v[r] = f2bf(acc[mi][ni][r]);
                *(short4v*)&YT[((size_t)bi * DM + col) * SEQ + rl0] = v;
            }
        }
    } else {
        short* Yh = (short*)Yv;
        float* Yf = (float*)Yv;
#pragma unroll
        for (int mi = 0; mi < 4; ++mi) {
#pragma unroll
            for (int ni = 0; ni < 4; ++ni) {
                const int row0 = bm + wr + mi * 16 + lhi * 4;
                const int col  = bn + wc + ni * 16 + l16;
#pragma unroll
                for (int r = 0; r < 4; ++r) {
                    if (fY) Yf[(size_t)(row0 + r) * N + col] = acc[mi][ni][r];
                    else    Yh[(size_t)(row0 + r) * N + col] = f2bf(acc[mi][ni][r]);
                }
            }
        }
    }
}

// ---------------------------------------------------------------------------
// Flash attention (causal + key mask). One block per (b,h,64-row qtile),
// 4 waves x 16 q-rows. KVBLK=64. K and V^T staged via swizzled gload_lds.
// Diagonal tile is the only one paying the causal compare. q-tiles dispatched
// longest-first.
// ---------------------------------------------------------------------------
__global__ __launch_bounds__(256)
void attn_fwd(const short* __restrict__ Q, const short* __restrict__ Kp,
              const short* __restrict__ VT, const int* __restrict__ amask,
              short* __restrict__ ctx) {
    __shared__ short k_lds[64 * 64];     // K tile  [k][d]   (swizzled)
    __shared__ short v_lds[64 * 64];     // V^T tile [d][k]  (swizzled)
    __shared__ short p_lds[4][16 * 64];  // per-wave P buffer (swizzled)

    const int t    = threadIdx.x;
    const int lane = t & 63;
    const int l16  = lane & 15;
    const int lhi  = lane >> 4;
    const int w    = t >> 6;
    const int qt   = (int)(gridDim.x - 1 - blockIdx.x);  // longest-first
    const int bh   = blockIdx.y;
    const int b    = bh >> 4;
    const int h    = bh & 15;

    const short* Qh  = Q  + (size_t)b * SEQ * DM + h * 64;
    const short* Kh  = Kp + (size_t)b * SEQ * DM + h * 64;
    const short* Vh  = VT + (size_t)bh * 64 * SEQ;
    const int*   mb  = amask + b * SEQ;

    const int q0 = qt * 64 + w * 16;

    bf16x8 qf[2];
#pragma unroll
    for (int df = 0; df < 2; ++df)
        qf[df] = *(const bf16x8*)&Qh[(size_t)(q0 + l16) * DM + df * 32 + lhi * 8];

    float m_r[4], l_r[4];
    f32x4 o[4] = {};
#pragma unroll
    for (int r = 0; r < 4; ++r) { m_r[r] = -1e30f; l_r[r] = 0.f; }

    // staging chunks: 512 per array (64 rows x 8), 2 per thread
    const int c0 = t, c1 = t + 256;
    const int r0 = c0 >> 3, p0 = (c0 & 7) ^ (r0 & 7);
    const int r1 = c1 >> 3, p1 = (c1 & 7) ^ (r1 & 7);

    for (int kt = 0; kt <= qt; ++kt) {
        __syncthreads();
        gload_lds16(Kh + (size_t)(kt * 64 + r0) * DM + p0 * 8, k_lds + c0 * 8);
        gload_lds16(Kh + (size_t)(kt * 64 + r1) * DM + p1 * 8, k_lds + c1 * 8);
        gload_lds16(Vh + (size_t)r0 * SEQ + kt * 64 + p0 * 8, v_lds + c0 * 8);
        gload_lds16(Vh + (size_t)r1 * SEQ + kt * 64 + p1 * 8, v_lds + c1 * 8);
        __syncthreads();

        // S = Q K^T : 4 col-fragments x K=64
        f32x4 s[4] = {};
#pragma unroll
        for (int nf = 0; nf < 4; ++nf) {
            const int row = nf * 16 + l16;
#pragma unroll
            for (int df = 0; df < 2; ++df) {
                bf16x8 kf = *(const bf16x8*)&k_lds[row * 64 + ((df * 4 + lhi) ^ (row & 7)) * 8];
                s[nf] = MFMA16(qf[df], kf, s[nf]);
            }
        }

        // scale + masks; per-row tile max
        float p[4][4], tmax[4];
#pragma unroll
        for (int r = 0; r < 4; ++r) tmax[r] = -1e30f;
        const bool diag = (kt == qt);
#pragma unroll
        for (int nf = 0; nf < 4; ++nf) {
            const int   kc     = kt * 64 + nf * 16 + l16;
            const float mvalid = (mb[kc] != 0) ? 0.f : -1e30f;
#pragma unroll
            for (int r = 0; r < 4; ++r) {
                float sv = s[nf][r] * 0.125f + mvalid;
                if (diag && kc > q0 + lhi * 4 + r) sv = -1e30f;
                p[nf][r] = sv;
                tmax[r]  = fmaxf(tmax[r], sv);
            }
        }
#pragma unroll
        for (int r = 0; r < 4; ++r)
#pragma unroll
            for (int xm = 1; xm < 16; xm <<= 1)
                tmax[r] = fmaxf(tmax[r], __shfl_xor(tmax[r], xm, 64));

        float alpha[4], rs[4];
#pragma unroll
        for (int r = 0; r < 4; ++r) {
            const float mnew = fmaxf(m_r[r], tmax[r]);
            alpha[r] = __expf(m_r[r] - mnew);
            m_r[r]   = mnew;
            float acc_s = 0.f;
#pragma unroll
            for (int nf = 0; nf < 4; ++nf) {
                const float pv = __expf(p[nf][r] - mnew);
                p[nf][r] = pv;
                acc_s += pv;
            }
            rs[r] = acc_s;
        }
#pragma unroll
        for (int r = 0; r < 4; ++r) {
#pragma unroll
            for (int xm = 1; xm < 16; xm <<= 1)
                rs[r] += __shfl_xor(rs[r], xm, 64);
            l_r[r] = alpha[r] * l_r[r] + rs[r];
        }
#pragma unroll
        for (int df = 0; df < 4; ++df)
#pragma unroll
            for (int r = 0; r < 4; ++r)
                o[df][r] *= alpha[r];

        // P (C-layout) -> swizzled LDS -> MFMA A fragments
#pragma unroll
        for (int nf = 0; nf < 4; ++nf)
#pragma unroll
            for (int r = 0; r < 4; ++r) {
                const int prow = lhi * 4 + r;
                const int pcol = (nf * 16 + l16) ^ ((prow & 7) << 3);
                p_lds[w][prow * 64 + pcol] = f2bf(p[nf][r]);
            }
        asm volatile("s_waitcnt lgkmcnt(0)" ::: "memory");

        const bf16x8 pa0 = *(const bf16x8*)&p_lds[w][l16 * 64 + ((lhi)     ^ (l16 & 7)) * 8];
        const bf16x8 pa1 = *(const bf16x8*)&p_lds[w][l16 * 64 + ((4 + lhi) ^ (l16 & 7)) * 8];
#pragma unroll
        for (int df = 0; df < 4; ++df) {
            const int row = df * 16 + l16;
            bf16x8 vf0 = *(const bf16x8*)&v_lds[row * 64 + ((lhi)     ^ (row & 7)) * 8];
            bf16x8 vf1 = *(const bf16x8*)&v_lds[row * 64 + ((4 + lhi) ^ (row & 7)) * 8];
            o[df] = MFMA16(pa0, vf0, o[df]);
            o[df] = MFMA16(pa1, vf1, o[df]);
        }
    }

    // epilogue: O / l -> ctx[b*SEQ + q][h*64 + d]  (always bf16)
#pragma unroll
    for (int r = 0; r < 4; ++r) {
        const float inv = 1.f / l_r[r];
        const int   qr  = q0 + lhi * 4 + r;
#pragma unroll
        for (int df = 0; df < 4; ++df)
            ctx[(size_t)(b * SEQ + qr) * DM + h * 64 + df * 16 + l16] =
                f2bf(o[df][r] * inv);
    }
}

// ---------------------------------------------------------------------------
extern "C" void kernel_launch(void* const* d_in, const int* in_sizes, int n_in,
                              void* d_out, int out_size, void* d_ws, size_t ws_size,
                              hipStream_t stream) {
    const void* query = d_in[0];
    const void* key   = d_in[1];
    const void* value = d_in[2];
    const int*  am    = (const int*)d_in[3];
    const void* Wq    = d_in[4];
    const void* Wk    = d_in[5];
    const void* Wv    = d_in[6];
    const void* Wo    = d_in[7];

    const size_t MTOK = (size_t)BATCH * SEQ;           // 8192 rows
    const size_t BUF  = MTOK * DM * sizeof(short);     // 16 MiB per buffer
    char*  ws   = (char*)d_ws;
    int*   flag = (int*)ws;                            // [0,4): dtype flag
    short* qp   = (short*)(ws + 1024 + 0 * BUF);
    short* kp   = (short*)(ws + 1024 + 1 * BUF);
    short* vt   = (short*)(ws + 1024 + 2 * BUF);       // V^T [b,h,d][seq]
    short* ctx  = (short*)(ws + 1024 + 3 * BUF);

    detect_dtype<<<1, 256, 0, stream>>>((const unsigned short*)query, flag);

    const dim3 ggrid(MTOK / 128, DM / 128);  // (64, 8)
    gemm_dual<<<ggrid, 256, 0, stream>>>(query, Wq, qp, flag, 1, 1, 0, 0, DM, DM);
    gemm_dual<<<ggrid, 256, 0, stream>>>(key,   Wk, kp, flag, 1, 1, 0, 0, DM, DM);
    gemm_dual<<<ggrid, 256, 0, stream>>>(value, Wv, vt, flag, 1, 1, 0, 1, DM, DM);

    attn_fwd<<<dim3(SEQ / 64, BATCH * NH), 256, 0, stream>>>(qp, kp, vt, am, ctx);

    gemm_dual<<<ggrid, 256, 0, stream>>>(ctx, Wo, d_out, flag, 0, 1, 1, 0, DM, DM);
}

// Round 5
// 395.575 us; speedup vs baseline: 2.0061x; 1.4120x over previous
//
#include <hip/hip_runtime.h>
#include <hip/hip_bf16.h>

// ---------------------------------------------------------------------------
// MultiHeadAttention: B=4, L=2048, D_MODEL=1024, H=16, Dh=64, causal + key mask
// Round 5 = round 4 resubmitted verbatim (round 4 hit GPUAcquisitionTimeout;
// kernel never ran). Changes vs round 3:
// (1) one-time f32->bf16 convert pass (data proven f32 by round-1 NaN);
//     GEMMs now pure-bf16 gload_lds, BK=32 double-buffered 2-phase pipeline.
// (2) attention: paired q-tiles (qt, 31-qt) -> constant 33 tile-iters/block,
//     1024 blocks = exactly 4/CU sustained; K/V double-buffered 2-phase;
//     setprio around MFMA. Swizzles kept (round-3: bank conflicts -> 0).
// ---------------------------------------------------------------------------

#define SEQ   2048
#define DM    1024
#define NH    16
#define BATCH 4
#define NT    (SEQ / 64)   // 32 k/q tiles

typedef __attribute__((ext_vector_type(8))) short bf16x8;   // 8 bf16 (4 VGPRs)
typedef __attribute__((ext_vector_type(4))) short short4v;  // 4 bf16 (8B store)
typedef __attribute__((ext_vector_type(4))) float f32x4;    // MFMA C/D

#define MFMA16(a, b, c) __builtin_amdgcn_mfma_f32_16x16x32_bf16((a), (b), (c), 0, 0, 0)

// f32 -> bf16 bits, round-to-nearest-even
__device__ inline short f2bf(float f) {
    unsigned u = __float_as_uint(f);
    unsigned r = (u + 0x7fffu + ((u >> 16) & 1u)) >> 16;
    return (short)r;
}

// async global->LDS, 16B per lane. LDS dest must be linear: base + lane*16.
__device__ inline void gload_lds16(const short* g, short* l) {
    __builtin_amdgcn_global_load_lds(
        (const __attribute__((address_space(1))) unsigned int*)g,
        (__attribute__((address_space(3))) unsigned int*)l,
        16, 0, 0);
}

// ---------------------------------------------------------------------------
// dtype detector: flag = 1 -> f32, 0 -> bf16.
// ---------------------------------------------------------------------------
__global__ void detect_dtype(const unsigned short* __restrict__ q, int* __restrict__ flag) {
    __shared__ int tot;
    const int t = threadIdx.x;
    if (t == 0) tot = 0;
    __syncthreads();
    int cnt = 0;
    for (int i = t; i < 4096; i += 256) {
        const unsigned short s = q[2 * i];
        const int e = (s >> 7) & 0xff;
        cnt += (e >= 100 && e <= 140) ? 1 : 0;
    }
    atomicAdd(&tot, cnt);
    __syncthreads();
    if (t == 0) *flag = (tot < 2048) ? 1 : 0;
}

// ---------------------------------------------------------------------------
// Fused convert: two tensors (X then W) f32->bf16 (or bf16 copy), vec8.
// ---------------------------------------------------------------------------
__global__ __launch_bounds__(256)
void to_bf16_pair(const void* __restrict__ sx, short* __restrict__ dx, int nx,
                  const void* __restrict__ sw, short* __restrict__ dw, int nw,
                  const int* __restrict__ flag) {
    const int isf = *flag;
    const long total = (long)(nx + nw) >> 3;
    for (long idx = (long)blockIdx.x * blockDim.x + threadIdx.x; idx < total;
         idx += (long)gridDim.x * blockDim.x) {
        const long i = idx << 3;
        const void* s; short* d; long off;
        if (i < nx) { s = sx; d = dx; off = i; }
        else        { s = sw; d = dw; off = i - nx; }
        if (isf) {
            const float* sf = (const float*)s + off;
            const f32x4 lo = *(const f32x4*)sf, hi = *(const f32x4*)(sf + 4);
            bf16x8 r;
#pragma unroll
            for (int j = 0; j < 4; ++j) { r[j] = f2bf(lo[j]); r[j + 4] = f2bf(hi[j]); }
            *(bf16x8*)(d + off) = r;
        } else {
            *(bf16x8*)(d + off) = *(const bf16x8*)((const short*)s + off);
        }
    }
}

// ---------------------------------------------------------------------------
// GEMM:  Y[M][N] = X[M][K] @ W[N][K]^T  (bf16 in, f32 accumulate)
// 128x128 tile, 4 waves 2x2 of 64x64. BK=32, double-buffered 2-phase:
// STAGE(next) issued before compute(cur); one vmcnt(0)+barrier per tile.
// LDS tiles [128][32], 4-slot XOR swizzle (slot = chunk ^ (row&3)).
// yT=1: write Y^T per (b,head) slice (V^T for attention). fY: f32 output.
// ---------------------------------------------------------------------------
__global__ __launch_bounds__(256)
void gemm_2ph(const short* __restrict__ X, const short* __restrict__ W,
              void* __restrict__ Yv, const int* __restrict__ flag,
              int yDyn, int yT, int N, int K) {
    __shared__ short lds_a[2][128 * 32];
    __shared__ short lds_b[2][128 * 32];

    const bool fY = yDyn && *flag;

    const int t    = threadIdx.x;
    const int lane = t & 63;
    const int l16  = lane & 15;
    const int lhi  = lane >> 4;
    const int w    = t >> 6;
    const int wr   = (w >> 1) * 64;
    const int wc   = (w & 1) * 64;
    const int bm   = blockIdx.x * 128;
    const int bn   = blockIdx.y * 128;

    f32x4 acc[4][4] = {};

    // staging: 512 chunks of 8 bf16 per operand; 2 per thread
    const int c0 = t, c1 = t + 256;
    const int r0 = c0 >> 2, s0 = (c0 & 3) ^ (r0 & 3);
    const int r1 = c1 >> 2, s1 = (c1 & 3) ^ (r1 & 3);
    const short* Xb = X + (size_t)bm * K;
    const short* Wb = W + (size_t)bn * K;

    auto stage = [&](int buf, int kt) {
        gload_lds16(Xb + (size_t)r0 * K + kt + s0 * 8, &lds_a[buf][c0 * 8]);
        gload_lds16(Xb + (size_t)r1 * K + kt + s1 * 8, &lds_a[buf][c1 * 8]);
        gload_lds16(Wb + (size_t)r0 * K + kt + s0 * 8, &lds_b[buf][c0 * 8]);
        gload_lds16(Wb + (size_t)r1 * K + kt + s1 * 8, &lds_b[buf][c1 * 8]);
    };

    stage(0, 0);
    asm volatile("s_waitcnt vmcnt(0)" ::: "memory");
    __builtin_amdgcn_s_barrier();

    int cur = 0;
    const int NIT = K / 32;
    for (int it = 0; it < NIT; ++it) {
        if (it + 1 < NIT) stage(cur ^ 1, (it + 1) * 32);

        bf16x8 af[4], bfr[4];
#pragma unroll
        for (int mi = 0; mi < 4; ++mi) {
            const int row = wr + mi * 16 + l16;
            af[mi] = *(const bf16x8*)&lds_a[cur][row * 32 + (lhi ^ (row & 3)) * 8];
        }
#pragma unroll
        for (int ni = 0; ni < 4; ++ni) {
            const int row = wc + ni * 16 + l16;
            bfr[ni] = *(const bf16x8*)&lds_b[cur][row * 32 + (lhi ^ (row & 3)) * 8];
        }
#pragma unroll
        for (int mi = 0; mi < 4; ++mi)
#pragma unroll
            for (int ni = 0; ni < 4; ++ni)
                acc[mi][ni] = MFMA16(af[mi], bfr[ni], acc[mi][ni]);

        asm volatile("s_waitcnt vmcnt(0)" ::: "memory");
        __builtin_amdgcn_s_barrier();
        cur ^= 1;
    }

    // epilogue: C/D layout col = lane&15, row = (lane>>4)*4 + reg
    if (yT) {
        short* YT = (short*)Yv;
#pragma unroll
        for (int mi = 0; mi < 4; ++mi) {
#pragma unroll
            for (int ni = 0; ni < 4; ++ni) {
                const int row0 = bm + wr + mi * 16 + lhi * 4;
                const int col  = bn + wc + ni * 16 + l16;
                const int bi   = row0 >> 11;         // / SEQ
                const int rl0  = row0 & (SEQ - 1);
                short4v v;
#pragma unroll
                for (int r = 0; r < 4; ++r) v[r] = f2bf(acc[mi][ni][r]);
                *(short4v*)&YT[((size_t)bi * DM + col) * SEQ + rl0] = v;
            }
        }
    } else {
        short* Yh = (short*)Yv;
        float* Yf = (float*)Yv;
#pragma unroll
        for (int mi = 0; mi < 4; ++mi) {
#pragma unroll
            for (int ni = 0; ni < 4; ++ni) {
                const int row0 = bm + wr + mi * 16 + lhi * 4;
                const int col  = bn + wc + ni * 16 + l16;
#pragma unroll
                for (int r = 0; r < 4; ++r) {
                    if (fY) Yf[(size_t)(row0 + r) * N + col] = acc[mi][ni][r];
                    else    Yh[(size_t)(row0 + r) * N + col] = f2bf(acc[mi][ni][r]);
                }
            }
        }
    }
}

// ---------------------------------------------------------------------------
// Flash attention, paired q-tiles: block x handles qt = x then qt = NT-1-x
// (constant 33 tile-iters). 4 waves x 16 q-rows, KVBLK=64, K/V double-buffered
// 2-phase. Swizzled LDS (round-3 verified, conflicts = 0).
// ---------------------------------------------------------------------------
__global__ __launch_bounds__(256, 4)
void attn_fwd(const short* __restrict__ Q, const short* __restrict__ Kp,
              const short* __restrict__ VT, const int* __restrict__ amask,
              short* __restrict__ ctx) {
    __shared__ short k_lds[2][64 * 64];   // K tile  [k][d]   (swizzled)
    __shared__ short v_lds[2][64 * 64];   // V^T tile [d][k]  (swizzled)
    __shared__ short p_lds[4][16 * 64];   // per-wave P buffer (swizzled)

    const int t    = threadIdx.x;
    const int lane = t & 63;
    const int l16  = lane & 15;
    const int lhi  = lane >> 4;
    const int w    = t >> 6;
    const int xp   = blockIdx.x;          // 0..NT/2-1
    const int bh   = blockIdx.y;
    const int b    = bh >> 4;
    const int h    = bh & 15;

    const short* Qh = Q  + (size_t)b * SEQ * DM + h * 64;
    const short* Kh = Kp + (size_t)b * SEQ * DM + h * 64;
    const short* Vh = VT + (size_t)bh * 64 * SEQ;
    const int*   mb = amask + b * SEQ;

    // staging chunks: 512 per array (64 rows x 8), 2 per thread
    const int c0 = t, c1 = t + 256;
    const int r0 = c0 >> 3, p0 = (c0 & 7) ^ (r0 & 7);
    const int r1 = c1 >> 3, p1 = (c1 & 7) ^ (r1 & 7);

    auto stageKV = [&](int buf, int kt) {
        gload_lds16(Kh + (size_t)(kt * 64 + r0) * DM + p0 * 8, &k_lds[buf][c0 * 8]);
        gload_lds16(Kh + (size_t)(kt * 64 + r1) * DM + p1 * 8, &k_lds[buf][c1 * 8]);
        gload_lds16(Vh + (size_t)r0 * SEQ + kt * 64 + p0 * 8, &v_lds[buf][c0 * 8]);
        gload_lds16(Vh + (size_t)r1 * SEQ + kt * 64 + p1 * 8, &v_lds[buf][c1 * 8]);
    };

    for (int ph = 0; ph < 2; ++ph) {
        const int qt = ph ? (NT - 1 - xp) : xp;
        const int q0 = qt * 64 + w * 16;

        bf16x8 qf0 = *(const bf16x8*)&Qh[(size_t)(q0 + l16) * DM + lhi * 8];
        bf16x8 qf1 = *(const bf16x8*)&Qh[(size_t)(q0 + l16) * DM + 32 + lhi * 8];

        float m_r[4], l_r[4];
        f32x4 o[4] = {};
#pragma unroll
        for (int r = 0; r < 4; ++r) { m_r[r] = -1e30f; l_r[r] = 0.f; }

        stageKV(0, 0);
        asm volatile("s_waitcnt vmcnt(0)" ::: "memory");
        __builtin_amdgcn_s_barrier();

        int cur = 0;
        for (int kt = 0; kt <= qt; ++kt) {
            if (kt < qt) stageKV(cur ^ 1, kt + 1);

            // S = Q K^T : 4 col-fragments x K=64
            f32x4 s[4] = {};
            __builtin_amdgcn_s_setprio(1);
#pragma unroll
            for (int nf = 0; nf < 4; ++nf) {
                const int row = nf * 16 + l16;
                bf16x8 kf0 = *(const bf16x8*)&k_lds[cur][row * 64 + ((lhi)     ^ (row & 7)) * 8];
                bf16x8 kf1 = *(const bf16x8*)&k_lds[cur][row * 64 + ((4 + lhi) ^ (row & 7)) * 8];
                s[nf] = MFMA16(qf0, kf0, s[nf]);
                s[nf] = MFMA16(qf1, kf1, s[nf]);
            }
            __builtin_amdgcn_s_setprio(0);

            // scale + masks; per-row tile max
            float p[4][4], tmax[4];
#pragma unroll
            for (int r = 0; r < 4; ++r) tmax[r] = -1e30f;
            const bool diag = (kt == qt);
#pragma unroll
            for (int nf = 0; nf < 4; ++nf) {
                const int   kc     = kt * 64 + nf * 16 + l16;
                const float mvalid = (mb[kc] != 0) ? 0.f : -1e30f;
#pragma unroll
                for (int r = 0; r < 4; ++r) {
                    float sv = s[nf][r] * 0.125f + mvalid;
                    if (diag && kc > q0 + lhi * 4 + r) sv = -1e30f;
                    p[nf][r] = sv;
                    tmax[r]  = fmaxf(tmax[r], sv);
                }
            }
#pragma unroll
            for (int r = 0; r < 4; ++r)
#pragma unroll
                for (int xm = 1; xm < 16; xm <<= 1)
                    tmax[r] = fmaxf(tmax[r], __shfl_xor(tmax[r], xm, 64));

            float alpha[4], rs[4];
#pragma unroll
            for (int r = 0; r < 4; ++r) {
                const float mnew = fmaxf(m_r[r], tmax[r]);
                alpha[r] = __expf(m_r[r] - mnew);
                m_r[r]   = mnew;
                float acc_s = 0.f;
#pragma unroll
                for (int nf = 0; nf < 4; ++nf) {
                    const float pv = __expf(p[nf][r] - mnew);
                    p[nf][r] = pv;
                    acc_s += pv;
                }
                rs[r] = acc_s;
            }
#pragma unroll
            for (int r = 0; r < 4; ++r) {
#pragma unroll
                for (int xm = 1; xm < 16; xm <<= 1)
                    rs[r] += __shfl_xor(rs[r], xm, 64);
                l_r[r] = alpha[r] * l_r[r] + rs[r];
            }
#pragma unroll
            for (int df = 0; df < 4; ++df)
#pragma unroll
                for (int r = 0; r < 4; ++r)
                    o[df][r] *= alpha[r];

            // P (C-layout) -> swizzled LDS -> MFMA A fragments
#pragma unroll
            for (int nf = 0; nf < 4; ++nf)
#pragma unroll
                for (int r = 0; r < 4; ++r) {
                    const int prow = lhi * 4 + r;
                    const int pcol = (nf * 16 + l16) ^ ((prow & 7) << 3);
                    p_lds[w][prow * 64 + pcol] = f2bf(p[nf][r]);
                }
            asm volatile("s_waitcnt lgkmcnt(0)" ::: "memory");

            const bf16x8 pa0 = *(const bf16x8*)&p_lds[w][l16 * 64 + ((lhi)     ^ (l16 & 7)) * 8];
            const bf16x8 pa1 = *(const bf16x8*)&p_lds[w][l16 * 64 + ((4 + lhi) ^ (l16 & 7)) * 8];
            __builtin_amdgcn_s_setprio(1);
#pragma unroll
            for (int df = 0; df < 4; ++df) {
                const int row = df * 16 + l16;
                bf16x8 vf0 = *(const bf16x8*)&v_lds[cur][row * 64 + ((lhi)     ^ (row & 7)) * 8];
                bf16x8 vf1 = *(const bf16x8*)&v_lds[cur][row * 64 + ((4 + lhi) ^ (row & 7)) * 8];
                o[df] = MFMA16(pa0, vf0, o[df]);
                o[df] = MFMA16(pa1, vf1, o[df]);
            }
            __builtin_amdgcn_s_setprio(0);

            asm volatile("s_waitcnt vmcnt(0)" ::: "memory");
            __builtin_amdgcn_s_barrier();
            cur ^= 1;
        }

        // epilogue: O / l -> ctx[b*SEQ + q][h*64 + d]
#pragma unroll
        for (int r = 0; r < 4; ++r) {
            const float inv = 1.f / l_r[r];
            const int   qr  = q0 + lhi * 4 + r;
#pragma unroll
            for (int df = 0; df < 4; ++df)
                ctx[(size_t)(b * SEQ + qr) * DM + h * 64 + df * 16 + l16] =
                    f2bf(o[df][r] * inv);
        }
    }
}

// ---------------------------------------------------------------------------
extern "C" void kernel_launch(void* const* d_in, const int* in_sizes, int n_in,
                              void* d_out, int out_size, void* d_ws, size_t ws_size,
                              hipStream_t stream) {
    const void* query = d_in[0];
    const void* key   = d_in[1];
    const void* value = d_in[2];
    const int*  am    = (const int*)d_in[3];
    const void* Wq    = d_in[4];
    const void* Wk    = d_in[5];
    const void* Wv    = d_in[6];
    const void* Wo    = d_in[7];

    const size_t MTOK = (size_t)BATCH * SEQ;           // 8192 rows
    const size_t BUF  = MTOK * DM * sizeof(short);     // 16 MiB
    const size_t WBUF = (size_t)DM * DM * sizeof(short); // 2 MiB
    const int    NX   = (int)(MTOK * DM);              // 8M elems
    const int    NW   = DM * DM;                       // 1M elems

    char*  ws   = (char*)d_ws;
    int*   flag = (int*)ws;
    short* cx   = (short*)(ws + 1024);                 // converted X (later ctx)
    short* w1   = (short*)(ws + 1024 + BUF);           // converted W
    short* qp   = (short*)(ws + 1024 + BUF + WBUF);
    short* kp   = (short*)(ws + 1024 + 2 * BUF + WBUF);
    short* vt   = (short*)(ws + 1024 + 3 * BUF + WBUF); // V^T [b,h,d][seq]
    short* ctx  = cx;                                   // reuse after gemm3

    detect_dtype<<<1, 256, 0, stream>>>((const unsigned short*)query, flag);

    const dim3 ggrid(MTOK / 128, DM / 128);  // (64, 8)
    const dim3 cgrid(1024);

    to_bf16_pair<<<cgrid, 256, 0, stream>>>(query, cx, NX, Wq, w1, NW, flag);
    gemm_2ph<<<ggrid, 256, 0, stream>>>(cx, w1, qp, flag, 0, 0, DM, DM);

    to_bf16_pair<<<cgrid, 256, 0, stream>>>(key, cx, NX, Wk, w1, NW, flag);
    gemm_2ph<<<ggrid, 256, 0, stream>>>(cx, w1, kp, flag, 0, 0, DM, DM);

    to_bf16_pair<<<cgrid, 256, 0, stream>>>(value, cx, NX, Wv, w1, NW, flag);
    gemm_2ph<<<ggrid, 256, 0, stream>>>(cx, w1, vt, flag, 0, 1, DM, DM);

    to_bf16_pair<<<cgrid, 256, 0, stream>>>(Wo, w1, NW, Wo, w1, 0, flag);

    attn_fwd<<<dim3(NT / 2, BATCH * NH), 256, 0, stream>>>(qp, kp, vt, am, ctx);

    gemm_2ph<<<ggrid, 256, 0, stream>>>(ctx, w1, d_out, flag, 1, 0, DM, DM);
}